// Round 8
// baseline (23223.305 us; speedup 1.0000x reference)
//
#include <hip/hip_runtime.h>
#include <math.h>

// ---------------- problem constants ----------------
constexpr int MM = 8;      // batch of GPs
constexpr int NC = 1024;   // context points
constexpr int NT = 512;    // target points
constexpr int GRID = 768;  // persistent blocks; 3/CU (LDS 48640*3<=160K, VGPR<=170)
constexpr int GPB  = GRID / MM;  // 96 blocks per GP group

// Workspace layout (floats):
//  Kb   : MM*1024*1024   (K raw/Schur; G only written at final step)
//  Ab   : MM*1024*1024   (diag-block inverses + L panels -> A = L^-1)
//  Tb   : MM*512*512     (trinv temp; S1/S2 at predict)
//  Ktc  : MM*NT*NC
//  alpha: MM*1024
//  acc  : MM*8   ([0]=T1 [1]=T2 [2]=trG, atomically accumulated)
constexpr size_t OFF_A     = (size_t)MM * 1024 * 1024;
constexpr size_t OFF_T     = OFF_A * 2;
constexpr size_t OFF_KTC   = OFF_T + (size_t)MM * 512 * 512;
constexpr size_t OFF_ALPHA = OFF_KTC + (size_t)MM * NT * NC;
constexpr size_t OFF_ACC   = OFF_ALPHA + (size_t)MM * 1024;

#define S5 2.2360679775f

// ---------------- per-group barrier, two protocols ---------------------------
// FULL (any mapping): per-block agent __threadfence (L2 wb/inv) around slot/gen.
// CHEAP (group provably on ONE XCD via HW_REG_XCC_ID): intra-XCD L2 is
// shared+coherent; __syncthreads() drains vmcnt(0) (stores in L2), and all
// cross-block reads are volatile (L1-bypass) — no cache maintenance needed.
struct GBar {
  unsigned slot[GPB][16];  // one 64B line per block
  unsigned gen[16];
  unsigned xcd[GPB][16];   // posted XCC_ID per block (re-written each launch)
};
__device__ GBar g_bar2[MM];

__device__ __forceinline__ unsigned bar_base(int m) {
  return __hip_atomic_load(&g_bar2[m].gen[0], __ATOMIC_RELAXED, __HIP_MEMORY_SCOPE_AGENT);
}

__device__ __forceinline__ void gbar_full(int m, int gb, unsigned ph) {
  __syncthreads();
  GBar* b = &g_bar2[m];
  const int tid = threadIdx.x;
  if (gb == 0) {
    if (tid >= 1 && tid < GPB) {
      while (__hip_atomic_load(&b->slot[tid][0], __ATOMIC_RELAXED, __HIP_MEMORY_SCOPE_AGENT) < ph)
        __builtin_amdgcn_s_sleep(2);
    }
    __syncthreads();
    if (tid == 0) {
      __threadfence();  // release own writes + acquire others'
      __hip_atomic_store(&b->gen[0], ph, __ATOMIC_RELAXED, __HIP_MEMORY_SCOPE_AGENT);
    }
    __syncthreads();
  } else {
    if (tid == 0) {
      __threadfence();  // release this block's global writes
      __hip_atomic_store(&b->slot[gb][0], ph, __ATOMIC_RELAXED, __HIP_MEMORY_SCOPE_AGENT);
      while (__hip_atomic_load(&b->gen[0], __ATOMIC_RELAXED, __HIP_MEMORY_SCOPE_AGENT) < ph)
        __builtin_amdgcn_s_sleep(8);
      __threadfence();  // acquire before reading others' data
    }
    __syncthreads();
  }
}

__device__ __forceinline__ void gbar_cheap(int m, int gb, unsigned ph) {
  __syncthreads();  // compiler emits s_waitcnt vmcnt(0) before s_barrier
  GBar* b = &g_bar2[m];
  const int tid = threadIdx.x;
  if (gb == 0) {
    if (tid >= 1 && tid < GPB) {
      while (__hip_atomic_load(&b->slot[tid][0], __ATOMIC_RELAXED, __HIP_MEMORY_SCOPE_AGENT) < ph)
        __builtin_amdgcn_s_sleep(2);
    }
    __syncthreads();
    if (tid == 0) {
      asm volatile("s_waitcnt vmcnt(0)" ::: "memory");
      __hip_atomic_store(&b->gen[0], ph, __ATOMIC_RELAXED, __HIP_MEMORY_SCOPE_AGENT);
    }
    __syncthreads();
  } else {
    if (tid == 0) {
      asm volatile("s_waitcnt vmcnt(0)" ::: "memory");
      __hip_atomic_store(&b->slot[gb][0], ph, __ATOMIC_RELAXED, __HIP_MEMORY_SCOPE_AGENT);
      while (__hip_atomic_load(&b->gen[0], __ATOMIC_RELAXED, __HIP_MEMORY_SCOPE_AGENT) < ph)
        __builtin_amdgcn_s_sleep(8);
    }
    __syncthreads();
  }
}

__device__ __forceinline__ void gbar(int m, int gb, unsigned& ph, int cheap) {
  if (cheap) gbar_cheap(m, gb, ph); else gbar_full(m, gb, ph);
  ph++;
}

__device__ __forceinline__ float sigmf(float x) { return 1.0f / (1.0f + expf(-x)); }
__device__ __forceinline__ float softplusf(float x) { return fmaxf(x, 0.0f) + log1pf(expf(-fabsf(x))); }

__device__ __forceinline__ void lt_decode(int x, int& i, int& j) {
  int ii = 0;
  while ((ii + 1) * (ii + 2) / 2 <= x) ++ii;
  i = ii; j = x - ii * (ii + 1) / 2;
}

// Shared-memory struct (~47.5 KB -> 3 blocks/CU: 3*48640 <= 163840)
struct SMem {
  float Ls[64 * 65];
  float Us[64 * 65];
  float Tt[32 * 33];
  float dvec[64];
  float As[16][68];
  float Bs[16][68];
  float xi[64][3];
  float xj[64][3];
  float ai[64];
  float aj[64];
  float red[4][4];
  unsigned bar0;
  int cheap;
};

// ---------------- 64x64-tile GEMM, register-prefetch double-buffered ---------
// A/B volatile: cross-block data bypasses (possibly stale) L1, reads the
// intra-XCD-coherent L2. Streaming reads -> ~free.
template <int TA, int TB>
__device__ __forceinline__ void gemm64(const volatile float* __restrict__ A, int lda,
                                       const volatile float* __restrict__ B, int ldb,
                                       int kBeg, int kEnd, float acc[4][4], SMem& sm) {
  int tid = threadIdx.x, tx = tid & 15, ty = tid >> 4;
  float ra[4], rb[4];
  auto ldAB = [&](int k0) {
#pragma unroll
    for (int q = 0; q < 4; ++q) {
      int e = tid + (q << 8);
      if (TA) { int kk = e >> 6, r = e & 63; ra[q] = A[(size_t)(k0 + kk) * lda + r]; }
      else    { int r = e >> 4, kk = e & 15; ra[q] = A[(size_t)r * lda + k0 + kk]; }
      if (TB) { int c = e >> 4, kk = e & 15; rb[q] = B[(size_t)c * ldb + k0 + kk]; }
      else    { int kk = e >> 6, c = e & 63; rb[q] = B[(size_t)(k0 + kk) * ldb + c]; }
    }
  };
  ldAB(kBeg);
  for (int k0 = kBeg; k0 < kEnd; k0 += 16) {
    __syncthreads();
#pragma unroll
    for (int q = 0; q < 4; ++q) {
      int e = tid + (q << 8);
      if (TA) sm.As[e >> 6][e & 63] = ra[q]; else sm.As[e & 15][e >> 4] = ra[q];
      if (TB) sm.Bs[e & 15][e >> 4] = rb[q]; else sm.Bs[e >> 6][e & 63] = rb[q];
    }
    __syncthreads();
    if (k0 + 16 < kEnd) ldAB(k0 + 16);
#pragma unroll
    for (int kk = 0; kk < 16; ++kk) {
      float a[4], b[4];
#pragma unroll
      for (int i = 0; i < 4; ++i) a[i] = sm.As[kk][ty * 4 + i];
#pragma unroll
      for (int j = 0; j < 4; ++j) b[j] = sm.Bs[kk][tx * 4 + j];
#pragma unroll
      for (int i = 0; i < 4; ++i)
#pragma unroll
        for (int j = 0; j < 4; ++j) acc[i][j] = fmaf(a[i], b[j], acc[i][j]);
    }
  }
}

// ---------------- in-LDS 64x64 SPD factor + triangular inverse ---------------
__device__ void factor64(SMem& sm, float* Uout, int ldu) {
  int tid = threadIdx.x;
  int tx = tid & 15, ty = tid >> 4;
  for (int j = 0; j < 63; ++j) {
    float rinv = 1.0f / sm.Ls[j * 65 + j];
    for (int i = j + 1 + ty; i < 64; i += 16) {
      float lij = sm.Ls[i * 65 + j] * rinv;
      for (int c = j + 1 + tx; c <= i; c += 16) sm.Ls[i * 65 + c] -= lij * sm.Ls[c * 65 + j];
    }
    __syncthreads();
  }
  if (tid < 64) sm.dvec[tid] = 1.0f / sqrtf(sm.Ls[tid * 65 + tid]);
  __syncthreads();
  for (int e = tid; e < 4096; e += 256) { int r = e >> 6, c = e & 63; if (c <= r) sm.Ls[r * 65 + c] *= sm.dvec[c]; }
  __syncthreads();
  for (int e = tid; e < 64 * 65; e += 256) sm.Us[e] = 0.0f;
  __syncthreads();
  if (tid < 64) {
    int b = tid >> 5, c0 = tid & 31, base = b * 32, gc = base + c0;
    sm.Us[gc * 65 + gc] = 1.0f / sm.Ls[gc * 65 + gc];
    for (int r = c0 + 1; r < 32; ++r) {
      int gr = base + r;
      float acc = 0.0f;
      for (int l = c0; l < r; ++l) acc += sm.Ls[gr * 65 + base + l] * sm.Us[(base + l) * 65 + gc];
      sm.Us[gr * 65 + gc] = -acc / sm.Ls[gr * 65 + gr];
    }
  }
  __syncthreads();
  for (int e = tid; e < 1024; e += 256) {
    int r = e >> 5, c = e & 31;
    float acc = 0.0f;
    for (int l = c; l < 32; ++l) acc += sm.Ls[(32 + r) * 65 + l] * sm.Us[l * 65 + c];
    sm.Tt[r * 33 + c] = acc;
  }
  __syncthreads();
  for (int e = tid; e < 1024; e += 256) {
    int r = e >> 5, c = e & 31;
    float acc = 0.0f;
    for (int l = 0; l <= r; ++l) acc += sm.Us[(32 + r) * 65 + 32 + l] * sm.Tt[l * 33 + c];
    sm.Us[(32 + r) * 65 + c] = -acc;
  }
  __syncthreads();
  for (int e = tid; e < 4096; e += 256) { int r = e >> 6, c = e & 63; Uout[(size_t)r * ldu + c] = sm.Us[r * 65 + c]; }
}

// ---------------- phase bodies -----------------------------------------------

// Replicated Adam: all blocks, deterministic => bit-identical state everywhere.
__device__ void adam_all(const float* __restrict__ yc, const float* __restrict__ ws,
                         int pn, int tstep, int m, int tid, SMem& sm,
                         float praw[4], float pm[4], float pv[4],
                         float& ls, float& os, float& noi, float& cm) {
  const volatile float* al = ws + OFF_ALPHA + (size_t)m * 1024;
  const volatile float* accp = ws + OFF_ACC + m * 8;
  const float* ym = yc + (size_t)m * NC;
  float t4 = 0, t5 = 0, t6 = 0;
  for (int i = tid; i < pn; i += 256) {
    float a = al[i];
    t4 = fmaf(a, a, t4); t5 += a; t6 = fmaf(ym[i] - cm, a, t6);
  }
  for (int off = 32; off; off >>= 1) {
    t4 += __shfl_down(t4, off); t5 += __shfl_down(t5, off); t6 += __shfl_down(t6, off);
  }
  int wid = tid >> 6, lane = tid & 63;
  if (lane == 0) { sm.red[wid][0] = t4; sm.red[wid][1] = t5; sm.red[wid][2] = t6; }
  __syncthreads();
  t4 = sm.red[0][0] + sm.red[1][0] + sm.red[2][0] + sm.red[3][0];
  t5 = sm.red[0][1] + sm.red[1][1] + sm.red[2][1] + sm.red[3][1];
  t6 = sm.red[0][2] + sm.red[1][2] + sm.red[2][2] + sm.red[3][2];
  float T1 = accp[0], T2 = accp[1], t3 = accp[2];
  float fn = (float)pn;
  float g_ls = 0.5f / fn * (T1 - T2);
  float g_os = 0.5f / (fn * os) * (fn - noi * t3 - t6 + noi * t4);
  float g_no = 0.5f / fn * (t3 - t4);
  float g_c = -t5 / fn;
  float gr[4];
  gr[0] = g_ls * sigmf(praw[0]);
  gr[1] = g_os * sigmf(praw[1]);
  gr[2] = g_no * sigmf(praw[2]);
  gr[3] = g_c;
  float bc1 = 1.0f - powf(0.9f, (float)tstep);
  float bc2 = 1.0f - powf(0.999f, (float)tstep);
#pragma unroll
  for (int i = 0; i < 4; ++i) {
    float mv = 0.9f * pm[i] + 0.1f * gr[i];
    float vv = 0.999f * pv[i] + 0.001f * gr[i] * gr[i];
    pm[i] = mv; pv[i] = vv;
    praw[i] = praw[i] - 0.1f * (mv / bc1) / (sqrtf(vv / bc2) + 1e-8f);
  }
  ls = softplusf(praw[0]);
  os = softplusf(praw[1]);
  noi = softplusf(praw[2]) + 1e-4f;
  cm = praw[3];
  __syncthreads();  // protect sm.red before later phases reuse sm
}

__device__ void d_buildK(const float* __restrict__ xc, float* ws, int n, int job, int m,
                         int tid, SMem& sm, float ls, float os, float noi) {
  const float* xm = xc + (size_t)m * NC * 3;
  float* Km = ws + (size_t)m * 1048576;
  float* Am = ws + OFF_A + (size_t)m * 1048576;
  float il2 = 1.0f / (ls * ls);
  int bi, bj; lt_decode(job, bi, bj);
  if (tid < 64) {
    int r = bi * 64 + tid;
    sm.xi[tid][0] = xm[r * 3 + 0]; sm.xi[tid][1] = xm[r * 3 + 1]; sm.xi[tid][2] = xm[r * 3 + 2];
  } else if (tid < 128) {
    int lr = tid - 64; int r = bj * 64 + lr;
    sm.xj[lr][0] = xm[r * 3 + 0]; sm.xj[lr][1] = xm[r * 3 + 1]; sm.xj[lr][2] = xm[r * 3 + 2];
  }
  __syncthreads();
  if (job == 0) {
    for (int e = tid; e < 4096; e += 256) {
      int r = e >> 6, c = e & 63;
      float d0 = sm.xi[r][0] - sm.xj[c][0], d1 = sm.xi[r][1] - sm.xj[c][1], d2 = sm.xi[r][2] - sm.xj[c][2];
      float r2 = d0 * d0 + d1 * d1 + d2 * d2;
      float z = fmaxf(r2 * il2, 1e-12f);
      float dd = sqrtf(z);
      float kv = os * (1.0f + S5 * dd + (5.0f / 3.0f) * z) * expf(-S5 * dd);
      if (r == c) kv += noi;
      sm.Ls[r * 65 + c] = kv;
    }
    __syncthreads();
    factor64(sm, Am, n);
  } else {
    for (int e = tid; e < 4096; e += 256) {
      int r = e >> 6, c = e & 63;
      float d0 = sm.xi[r][0] - sm.xj[c][0], d1 = sm.xi[r][1] - sm.xj[c][1], d2 = sm.xi[r][2] - sm.xj[c][2];
      float r2 = d0 * d0 + d1 * d1 + d2 * d2;
      float z = fmaxf(r2 * il2, 1e-12f);
      float dd = sqrtf(z);
      float kv = os * (1.0f + S5 * dd + (5.0f / 3.0f) * z) * expf(-S5 * dd);
      if (bi == bj && r == c) kv += noi;
      Km[(size_t)(bi * 64 + r) * n + bj * 64 + c] = kv;
    }
  }
}

__device__ void d_trail(float* ws, int k, int n, int job, int m, int tid, SMem& sm) {
  int tx = tid & 15, ty = tid >> 4;
  float* Km = ws + (size_t)m * 1048576;
  float* Am = ws + OFF_A + (size_t)m * 1048576;
  const volatile float* Linv = Am + (size_t)(k * 64) * n + k * 64;
  int di, dj; lt_decode(job, di, dj);
  int i = k + 1 + di, j = k + 1 + dj;
  float pp[4][4] = {};
  gemm64<0, 1>(Km + (size_t)(i * 64) * n + k * 64, n, Linv, n, 0, 64, pp, sm);
  __syncthreads();
#pragma unroll
  for (int ii = 0; ii < 4; ++ii)
#pragma unroll
    for (int jj = 0; jj < 4; ++jj) sm.Ls[(ty * 4 + ii) * 65 + tx * 4 + jj] = pp[ii][jj];
  if (di == dj) {
    float* P = Am + (size_t)(i * 64) * n + k * 64;
#pragma unroll
    for (int ii = 0; ii < 4; ++ii)
#pragma unroll
      for (int jj = 0; jj < 4; ++jj) P[(size_t)(ty * 4 + ii) * n + tx * 4 + jj] = pp[ii][jj];
  } else {
#pragma unroll
    for (int ii = 0; ii < 4; ++ii)
#pragma unroll
      for (int jj = 0; jj < 4; ++jj) pp[ii][jj] = 0.0f;
    gemm64<0, 1>(Km + (size_t)(j * 64) * n + k * 64, n, Linv, n, 0, 64, pp, sm);
#pragma unroll
    for (int ii = 0; ii < 4; ++ii)
#pragma unroll
      for (int jj = 0; jj < 4; ++jj) sm.Us[(ty * 4 + ii) * 65 + tx * 4 + jj] = pp[ii][jj];
  }
  __syncthreads();
  float acc[4][4] = {};
  {
    const float* Bsrc = (di == dj) ? sm.Ls : sm.Us;
    for (int l = 0; l < 64; ++l) {
      float a[4], b[4];
#pragma unroll
      for (int ii = 0; ii < 4; ++ii) a[ii] = sm.Ls[(ty * 4 + ii) * 65 + l];
#pragma unroll
      for (int jj = 0; jj < 4; ++jj) b[jj] = Bsrc[(tx * 4 + jj) * 65 + l];
#pragma unroll
      for (int ii = 0; ii < 4; ++ii)
#pragma unroll
        for (int jj = 0; jj < 4; ++jj) acc[ii][jj] = fmaf(a[ii], b[jj], acc[ii][jj]);
    }
  }
  float* C = Km + (size_t)(i * 64) * n + j * 64;
  if (job == 0) {
    const volatile float* Cv = C;
    __syncthreads();
#pragma unroll
    for (int ii = 0; ii < 4; ++ii)
#pragma unroll
      for (int jj = 0; jj < 4; ++jj)
        sm.Ls[(ty * 4 + ii) * 65 + tx * 4 + jj] =
            Cv[(size_t)(ty * 4 + ii) * n + tx * 4 + jj] - acc[ii][jj];
    __syncthreads();
    factor64(sm, Am + (size_t)((k + 1) * 64) * n + (k + 1) * 64, n);
  } else {
    const volatile float* Cv = C;
#pragma unroll
    for (int ii = 0; ii < 4; ++ii)
#pragma unroll
      for (int jj = 0; jj < 4; ++jj)
        C[(size_t)(ty * 4 + ii) * n + tx * 4 + jj] =
            Cv[(size_t)(ty * 4 + ii) * n + tx * 4 + jj] - acc[ii][jj];
  }
}

__device__ void d_trinv64(float* ws, int n, int p, int m, int tid, SMem& sm) {
  int tx = tid & 15, ty = tid >> 4;
  float* Am = ws + OFF_A + (size_t)m * 1048576;
  const volatile float* Av = Am;
  int rb = (2 * p + 1) * 64, cb = 2 * p * 64;
  for (int e = tid; e < 4096; e += 256) {
    int r = e >> 6, c = e & 63;
    sm.Ls[r * 65 + c] = Av[(size_t)(rb + r) * n + cb + c];  // L21
    sm.Us[r * 65 + c] = Av[(size_t)(cb + r) * n + cb + c];  // A11
  }
  __syncthreads();
  float tt[4][4] = {};
  for (int l = 0; l < 64; ++l) {
    float a[4], b[4];
#pragma unroll
    for (int ii = 0; ii < 4; ++ii) a[ii] = sm.Ls[(ty * 4 + ii) * 65 + l];
#pragma unroll
    for (int jj = 0; jj < 4; ++jj) b[jj] = sm.Us[l * 65 + tx * 4 + jj];
#pragma unroll
    for (int ii = 0; ii < 4; ++ii)
#pragma unroll
      for (int jj = 0; jj < 4; ++jj) tt[ii][jj] = fmaf(a[ii], b[jj], tt[ii][jj]);
  }
  __syncthreads();
#pragma unroll
  for (int ii = 0; ii < 4; ++ii)
#pragma unroll
    for (int jj = 0; jj < 4; ++jj) sm.Ls[(ty * 4 + ii) * 65 + tx * 4 + jj] = tt[ii][jj];
  for (int e = tid; e < 4096; e += 256) {
    int r = e >> 6, c = e & 63;
    sm.Us[r * 65 + c] = Av[(size_t)(rb + r) * n + rb + c];  // A22
  }
  __syncthreads();
  float oo[4][4] = {};
  for (int l = 0; l < 64; ++l) {
    float a[4], b[4];
#pragma unroll
    for (int ii = 0; ii < 4; ++ii) a[ii] = sm.Us[(ty * 4 + ii) * 65 + l];
#pragma unroll
    for (int jj = 0; jj < 4; ++jj) b[jj] = sm.Ls[l * 65 + tx * 4 + jj];
#pragma unroll
    for (int ii = 0; ii < 4; ++ii)
#pragma unroll
      for (int jj = 0; jj < 4; ++jj) oo[ii][jj] = fmaf(a[ii], b[jj], oo[ii][jj]);
  }
#pragma unroll
  for (int ii = 0; ii < 4; ++ii)
#pragma unroll
    for (int jj = 0; jj < 4; ++jj)
      Am[(size_t)(rb + ty * 4 + ii) * n + cb + tx * 4 + jj] = -oo[ii][jj];
}

__device__ void d_trinvT(float* ws, int s, int n, int job, int m, int tid, SMem& sm) {
  int tx = tid & 15, ty = tid >> 4;
  float* Am = ws + OFF_A + (size_t)m * 1048576;
  float* Tm = ws + OFF_T + (size_t)m * 262144;
  int st = s >> 6;
  int p = job / (st * st), rem = job % (st * st);
  int ti = rem / st, tj = rem % st;
  int base = p * 2 * s;
  float acc[4][4] = {};
  gemm64<0, 0>(Am + (size_t)(base + s + ti * 64) * n + base, n,
               Am + (size_t)base * n + base + tj * 64, n, tj * 64, s, acc, sm);
  float* C = Tm + (size_t)p * s * s + (size_t)(ti * 64) * s + tj * 64;
#pragma unroll
  for (int ii = 0; ii < 4; ++ii)
#pragma unroll
    for (int jj = 0; jj < 4; ++jj) C[(size_t)(ty * 4 + ii) * s + tx * 4 + jj] = acc[ii][jj];
}

__device__ void d_trinvA(float* ws, int s, int n, int job, int m, int tid, SMem& sm) {
  int tx = tid & 15, ty = tid >> 4;
  float* Am = ws + OFF_A + (size_t)m * 1048576;
  const volatile float* Tm = ws + OFF_T + (size_t)m * 262144;
  int st = s >> 6;
  int p = job / (st * st), rem = job % (st * st);
  int ti = rem / st, tj = rem % st;
  int base = p * 2 * s;
  float acc[4][4] = {};
  gemm64<0, 0>(Am + (size_t)(base + s + ti * 64) * n + base + s, n,
               Tm + (size_t)p * s * s + tj * 64, s, 0, (ti + 1) * 64, acc, sm);
  float* C = Am + (size_t)(base + s + ti * 64) * n + base + tj * 64;
#pragma unroll
  for (int ii = 0; ii < 4; ++ii)
#pragma unroll
    for (int jj = 0; jj < 4; ++jj) C[(size_t)(ty * 4 + ii) * n + tx * 4 + jj] = -acc[ii][jj];
}

// syrk G=A^T A, fused: alpha += G(y-c), tr(G), a1 = <G,C> (G tile in regs;
// C recomputed from x). G stored only when writeG (final step).
__device__ void d_syrkAT(const float* __restrict__ yc, const float* __restrict__ xc,
                         float* ws, int n, int job, int m, int tid, SMem& sm,
                         float cm, float ls, float os, bool writeG) {
  int tx = tid & 15, ty = tid >> 4;
  const float* Am = ws + OFF_A + (size_t)m * 1048576;
  float* Gm = ws + (size_t)m * 1048576;
  const float* ym = yc + (size_t)m * NC;
  const float* xm = xc + (size_t)m * NC * 3;
  float* accp = ws + OFF_ACC + m * 8;
  float* al = ws + OFF_ALPHA + (size_t)m * 1024;
  int ib, jb; lt_decode(job, ib, jb);
  if (tid < 64) {
    int r = ib * 64 + tid;
    sm.ai[tid] = ym[r] - cm;
    sm.xi[tid][0] = xm[r * 3 + 0]; sm.xi[tid][1] = xm[r * 3 + 1]; sm.xi[tid][2] = xm[r * 3 + 2];
  } else if (tid < 128) {
    int lr = tid - 64; int r = jb * 64 + lr;
    sm.aj[lr] = ym[r] - cm;
    sm.xj[lr][0] = xm[r * 3 + 0]; sm.xj[lr][1] = xm[r * 3 + 1]; sm.xj[lr][2] = xm[r * 3 + 2];
  }
  float acc[4][4] = {};
  gemm64<1, 0>(Am + ib * 64, n, Am + jb * 64, n, ib * 64, n, acc, sm);
  if (writeG) {
#pragma unroll
    for (int ii = 0; ii < 4; ++ii)
#pragma unroll
      for (int jj = 0; jj < 4; ++jj) {
        int r = ty * 4 + ii, c = tx * 4 + jj;
        Gm[(size_t)(ib * 64 + r) * n + jb * 64 + c] = acc[ii][jj];
        if (ib != jb) Gm[(size_t)(jb * 64 + c) * n + ib * 64 + r] = acc[ii][jj];
      }
  }
  if (ib == jb && tx == ty) {
    atomicAdd(&accp[2], acc[0][0] + acc[1][1] + acc[2][2] + acc[3][3]);
  }
  float rowp[4];
#pragma unroll
  for (int i = 0; i < 4; ++i) {
    float s = 0.0f;
#pragma unroll
    for (int j = 0; j < 4; ++j) s = fmaf(acc[i][j], sm.aj[tx * 4 + j], s);
    rowp[i] = s;
  }
  float colp[4];
  if (ib != jb) {
#pragma unroll
    for (int j = 0; j < 4; ++j) {
      float s = 0.0f;
#pragma unroll
      for (int i = 0; i < 4; ++i) s = fmaf(acc[i][j], sm.ai[ty * 4 + i], s);
      colp[j] = s;
    }
  }
  float il2 = 1.0f / (ls * ls);
  float c53 = (5.0f / 3.0f) * os / ls;
  float a1 = 0.0f;
#pragma unroll
  for (int ii = 0; ii < 4; ++ii) {
    int r = ty * 4 + ii;
#pragma unroll
    for (int jj = 0; jj < 4; ++jj) {
      int c = tx * 4 + jj;
      float d0 = sm.xi[r][0] - sm.xj[c][0], d1 = sm.xi[r][1] - sm.xj[c][1], d2 = sm.xi[r][2] - sm.xj[c][2];
      float r2 = d0 * d0 + d1 * d1 + d2 * d2;
      float z = fmaxf(r2 * il2, 1e-12f);
      float dd = sqrtf(z);
      float Cv = c53 * z * (1.0f + S5 * dd) * expf(-S5 * dd);
      a1 = fmaf(acc[ii][jj], Cv, a1);
    }
  }
  a1 *= (ib == jb) ? 1.0f : 2.0f;
  for (int off = 32; off; off >>= 1) a1 += __shfl_down(a1, off);
  int wid = tid >> 6, lane = tid & 63;
  if (lane == 0) sm.red[wid][0] = a1;
  __syncthreads();
  if (tid == 0)
    atomicAdd(&accp[0], sm.red[0][0] + sm.red[1][0] + sm.red[2][0] + sm.red[3][0]);
  float* redA = &sm.As[0][0];
  float* redB = &sm.Bs[0][0];
#pragma unroll
  for (int i = 0; i < 4; ++i) redA[(ty * 4 + i) * 16 + tx] = rowp[i];
  if (ib != jb) {
#pragma unroll
    for (int j = 0; j < 4; ++j) redB[(tx * 4 + j) * 16 + ty] = colp[j];
  }
  __syncthreads();
  if (tid < 64) {
    float s = 0.0f;
#pragma unroll
    for (int q = 0; q < 16; ++q) s += redA[tid * 16 + q];
    atomicAdd(&al[ib * 64 + tid], s);
    if (ib != jb) {
      float s2 = 0.0f;
#pragma unroll
      for (int q = 0; q < 16; ++q) s2 += redB[tid * 16 + q];
      atomicAdd(&al[jb * 64 + tid], s2);
    }
  }
}

// a2 = alpha^T C alpha only (a1 fused into syrk; no G reads)
__device__ void d_reduce2(const float* __restrict__ xc, float* ws, int n, int job, int m,
                          int tid, SMem& sm, float ls, float os) {
  const float* xm = xc + (size_t)m * NC * 3;
  const volatile float* al = ws + OFF_ALPHA + (size_t)m * 1024;
  float* accp = ws + OFF_ACC + m * 8;
  float il2 = 1.0f / (ls * ls);
  float c53 = (5.0f / 3.0f) * os / ls;
  int bi, bj; lt_decode(job, bi, bj);
  float w = (bi == bj) ? 1.0f : 2.0f;
  if (tid < 64) {
    int r = bi * 64 + tid;
    sm.xi[tid][0] = xm[r * 3 + 0]; sm.xi[tid][1] = xm[r * 3 + 1]; sm.xi[tid][2] = xm[r * 3 + 2];
    sm.ai[tid] = al[r];
  } else if (tid < 128) {
    int lr = tid - 64; int r = bj * 64 + lr;
    sm.xj[lr][0] = xm[r * 3 + 0]; sm.xj[lr][1] = xm[r * 3 + 1]; sm.xj[lr][2] = xm[r * 3 + 2];
    sm.aj[lr] = al[r];
  }
  __syncthreads();
  float a2 = 0.0f;
  for (int e = tid; e < 4096; e += 256) {
    int r = e >> 6, c = e & 63;
    float d0 = sm.xi[r][0] - sm.xj[c][0], d1 = sm.xi[r][1] - sm.xj[c][1], d2 = sm.xi[r][2] - sm.xj[c][2];
    float r2 = d0 * d0 + d1 * d1 + d2 * d2;
    float z = fmaxf(r2 * il2, 1e-12f);
    float dd = sqrtf(z);
    float Cv = c53 * z * (1.0f + S5 * dd) * expf(-S5 * dd);
    a2 = fmaf(sm.ai[r] * sm.aj[c], Cv, a2);
  }
  a2 *= w;
  for (int off = 32; off; off >>= 1) a2 += __shfl_down(a2, off);
  int wid = tid >> 6, lane = tid & 63;
  if (lane == 0) sm.red[wid][1] = a2;
  __syncthreads();
  if (tid == 0) {
    atomicAdd(&accp[1], sm.red[0][1] + sm.red[1][1] + sm.red[2][1] + sm.red[3][1]);
  }
}

__device__ void d_buildKtc(const float* __restrict__ xt, const float* __restrict__ xc,
                           float* ws, int job, int m, int tid, SMem& sm, float ls, float os) {
  const float* xtm = xt + (size_t)m * NT * 3;
  const float* xm = xc + (size_t)m * NC * 3;
  float* Kt = ws + OFF_KTC + (size_t)m * NT * NC;
  float* Tm = ws + OFF_T + (size_t)m * 262144;  // S1 at Tm, S2 at Tm+NT
  float il2 = 1.0f / (ls * ls);
  if (job < 2) {
    int z = job * 256 + tid;
    Tm[z] = 0.0f; Tm[NT + z] = 0.0f;
  }
  int ti = job >> 4, tj = job & 15;
  if (tid < 64) {
    int r = ti * 64 + tid;
    sm.xi[tid][0] = xtm[r * 3 + 0]; sm.xi[tid][1] = xtm[r * 3 + 1]; sm.xi[tid][2] = xtm[r * 3 + 2];
  } else if (tid < 128) {
    int lr = tid - 64; int r = tj * 64 + lr;
    sm.xj[lr][0] = xm[r * 3 + 0]; sm.xj[lr][1] = xm[r * 3 + 1]; sm.xj[lr][2] = xm[r * 3 + 2];
  }
  __syncthreads();
  for (int e = tid; e < 4096; e += 256) {
    int r = e >> 6, c = e & 63;
    float d0 = sm.xi[r][0] - sm.xj[c][0], d1 = sm.xi[r][1] - sm.xj[c][1], d2 = sm.xi[r][2] - sm.xj[c][2];
    float r2 = d0 * d0 + d1 * d1 + d2 * d2;
    float z = fmaxf(r2 * il2, 1e-12f);
    float dd = sqrtf(z);
    float kv = os * (1.0f + S5 * dd + (5.0f / 3.0f) * z) * expf(-S5 * dd);
    Kt[(size_t)(ti * 64 + r) * NC + tj * 64 + c] = kv;
  }
}

__device__ void d_predW(float* ws, int job, int m, int tid, SMem& sm) {
  int tx = tid & 15, ty = tid >> 4;
  const volatile float* Kt = ws + OFF_KTC + (size_t)m * NT * NC;
  const volatile float* Gm = ws + (size_t)m * 1048576;
  const volatile float* al = ws + OFF_ALPHA + (size_t)m * 1024;
  float* S1 = ws + OFF_T + (size_t)m * 262144;
  float* S2 = S1 + NT;
  int ti = job >> 4, tj = job & 15;
  if (tid < 64) sm.aj[tid] = al[tj * 64 + tid];
  float acc[4][4] = {};
  gemm64<0, 0>(Kt + (size_t)(ti * 64) * NC, NC, Gm + tj * 64, 1024, 0, 1024, acc, sm);
  float s1p[4], s2p[4];
#pragma unroll
  for (int i = 0; i < 4; ++i) {
    float a1 = 0.0f, a2 = 0.0f;
    const volatile float* kr = Kt + (size_t)(ti * 64 + ty * 4 + i) * NC + tj * 64;
#pragma unroll
    for (int j = 0; j < 4; ++j) {
      float kv = kr[tx * 4 + j];
      a1 = fmaf(kv, sm.aj[tx * 4 + j], a1);
      a2 = fmaf(kv, acc[i][j], a2);
    }
    s1p[i] = a1; s2p[i] = a2;
  }
  __syncthreads();
  float* redA = &sm.As[0][0];
  float* redB = &sm.Bs[0][0];
#pragma unroll
  for (int i = 0; i < 4; ++i) {
    redA[(ty * 4 + i) * 16 + tx] = s1p[i];
    redB[(ty * 4 + i) * 16 + tx] = s2p[i];
  }
  __syncthreads();
  if (tid < 64) {
    float a1 = 0.0f, a2 = 0.0f;
#pragma unroll
    for (int q = 0; q < 16; ++q) { a1 += redA[tid * 16 + q]; a2 += redB[tid * 16 + q]; }
    atomicAdd(&S1[ti * 64 + tid], a1);
    atomicAdd(&S2[ti * 64 + tid], a2);
  }
}

// ---------------- persistent mega-kernel, XCD-confined per-m groups ----------
// 3 blocks/CU: 768 = 256 CU x 3 co-resident (LDS 3*48640 <= 160K, VGPR <= 170).
__global__ __launch_bounds__(256, 3) void k_gp(const float* __restrict__ xc,
                                               const float* __restrict__ yc,
                                               const float* __restrict__ xt,
                                               float* ws, float* out) {
  __shared__ SMem sm;
  const int bid = blockIdx.x;
  const int m  = bid % MM;
  const int gb = bid / MM;
  const int tid = threadIdx.x;

  if (tid == 0) sm.bar0 = bar_base(m);
  __syncthreads();
  unsigned ph = sm.bar0 + 1;

  // ---- runtime XCD-uniformity check (works for any GPB): post own XCC_ID,
  // full barrier, then tid0 serially verifies all-equal (once per launch).
  if (tid == 0) {
    unsigned x;
    asm volatile("s_getreg_b32 %0, hwreg(HW_REG_XCC_ID)" : "=s"(x));
    __hip_atomic_store(&g_bar2[m].xcd[gb][0], x, __ATOMIC_RELAXED, __HIP_MEMORY_SCOPE_AGENT);
  }
  gbar_full(m, gb, ph);
  ph++;
  if (tid == 0) {
    unsigned v0 = __hip_atomic_load(&g_bar2[m].xcd[0][0], __ATOMIC_RELAXED, __HIP_MEMORY_SCOPE_AGENT);
    int ok = 1;
    for (int i = 1; i < GPB; ++i)
      ok &= (__hip_atomic_load(&g_bar2[m].xcd[i][0], __ATOMIC_RELAXED, __HIP_MEMORY_SCOPE_AGENT) == v0);
    sm.cheap = ok;
  }
  __syncthreads();
  const int cheap = sm.cheap;

  // replicated per-block Adam/param state (bit-identical across blocks)
  float praw[4] = {0.f, 0.f, 0.f, 0.f};
  float pm[4]   = {0.f, 0.f, 0.f, 0.f};
  float pv[4]   = {0.f, 0.f, 0.f, 0.f};
  float ls = 0.69314718056f, os = 0.69314718056f;
  float noi = 0.69314718056f + 1e-4f, cm = 0.0f;

  for (int step = 0; step < 17; ++step) {
    const int n = step < 8 ? 512 : 1024;
    const int nb = n >> 6;
    const bool lastStep = (step == 16);

    // ---- merged phase: replicated Adam + buildK (factor(0,0) on gb0) ----
    if (step > 0) {
      adam_all(yc, ws, step <= 8 ? 512 : 1024, step, m, tid, sm,
               praw, pm, pv, ls, os, noi, cm);
    }
    {
      const int tot = nb * (nb + 1) / 2;
      if (gb == 0) {
        __syncthreads();
        __builtin_amdgcn_s_setprio(1);  // critical path: factor chain
        d_buildK(xc, ws, n, 0, m, tid, sm, ls, os, noi);  // job 0 = factor tile(0,0)
        __builtin_amdgcn_s_setprio(0);
      } else {
        for (int q = gb; q < tot; q += GPB - 1) {
          __syncthreads();
          d_buildK(xc, ws, n, q, m, tid, sm, ls, os, noi);
        }
      }
      gbar(m, gb, ph, cheap);
    }

    // ---- Cholesky trailing updates; gb0 owns the factor job; trinv64 pair
    // p=k>>1 folded onto gb=GPB-1 at odd k (inputs complete at barrier k-1).
    for (int k = 0; k <= nb - 2; ++k) {
      const int t = nb - 1 - k;
      const int tot = t * (t + 1) / 2;
      if (gb == 0) {
        if (k == 0) {  // zero alpha/acc (post-adam-read, pre-syrk-accumulate)
          float* al = ws + OFF_ALPHA + (size_t)m * 1024;
          for (int z = tid; z < 1024; z += 256) al[z] = 0.0f;
          if (tid < 8) ws[OFF_ACC + m * 8 + tid] = 0.0f;
        }
        __syncthreads();
        __builtin_amdgcn_s_setprio(1);  // critical path: Schur(0)+factor(k+1)
        d_trail(ws, k, n, 0, m, tid, sm);
        __builtin_amdgcn_s_setprio(0);
      } else {
        for (int q = gb; q < tot; q += GPB - 1) {
          __syncthreads();
          d_trail(ws, k, n, q, m, tid, sm);
        }
        if ((k & 1) && gb == GPB - 1) {
          __syncthreads();
          d_trinv64(ws, n, k >> 1, m, tid, sm);
        }
      }
      gbar(m, gb, ph, cheap);
    }

    for (int s = 128; s < n; s <<= 1) {  // trinv higher levels
      const int st = s >> 6;
      const int np = n / (2 * s);
      const int tot = np * st * st;
      for (int q = gb; q < tot; q += GPB) {
        __syncthreads();
        d_trinvT(ws, s, n, q, m, tid, sm);
      }
      if (s == 128 && gb == GPB - 1) {  // leftover trinv64 pair (nb/2-1)
        __syncthreads();
        d_trinv64(ws, n, nb / 2 - 1, m, tid, sm);
      }
      gbar(m, gb, ph, cheap);
      for (int q = gb; q < tot; q += GPB) {
        __syncthreads();
        d_trinvA(ws, s, n, q, m, tid, sm);
      }
      gbar(m, gb, ph, cheap);
    }

    {  // syrk + fused alpha/trace/a1; G stored only on the final step
      const int tot = nb * (nb + 1) / 2;
      for (int q = gb; q < tot; q += GPB) {
        __syncthreads();
        d_syrkAT(yc, xc, ws, n, q, m, tid, sm, cm, ls, os, lastStep);
      }
      gbar(m, gb, ph, cheap);
    }

    if (step < 16) {  // a2 = alpha^T C alpha (needs completed alpha)
      const int tot = nb * (nb + 1) / 2;
      for (int q = gb; q < tot; q += GPB) {
        __syncthreads();
        d_reduce2(xc, ws, n, q, m, tid, sm, ls, os);
      }
      gbar(m, gb, ph, cheap);
    }
  }

  // ---- prediction (per-m) ----
  {
    for (int q = gb; q < 128; q += GPB) {
      __syncthreads();
      d_buildKtc(xt, xc, ws, q, m, tid, sm, ls, os);
    }
    gbar(m, gb, ph, cheap);
    for (int q = gb; q < 128; q += GPB) {
      __syncthreads();
      d_predW(ws, q, m, tid, sm);
    }
    gbar(m, gb, ph, cheap);
    const volatile float* S1 = ws + OFF_T + (size_t)m * 262144;
    const volatile float* S2 = S1 + NT;
    for (int t = gb * 256 + tid; t < NT; t += GPB * 256) {
      out[(size_t)m * NT + t] = cm + S1[t];
      out[(size_t)MM * NT + (size_t)m * NT + t] = os + noi - S2[t];
    }
  }
}

// ---------------- host: single plain launch ----------------------------------
extern "C" void kernel_launch(void* const* d_in, const int* in_sizes, int n_in,
                              void* d_out, int out_size, void* d_ws, size_t ws_size,
                              hipStream_t stream) {
  const float* xc = (const float*)d_in[0];
  const float* yc = (const float*)d_in[1];
  const float* xt = (const float*)d_in[2];
  float* out = (float*)d_out;
  float* ws = (float*)d_ws;

  hipLaunchKernelGGL(k_gp, dim3(GRID), dim3(256), 0, stream, xc, yc, xt, ws, out);

  (void)in_sizes; (void)n_in; (void)out_size; (void)ws_size;
}

// Round 9
// 21055.247 us; speedup vs baseline: 1.1030x; 1.1030x over previous
//
#include <hip/hip_runtime.h>
#include <math.h>

// ---------------- problem constants ----------------
constexpr int MM = 8;        // batch of GPs = number of XCDs
constexpr int NC = 1024;     // context points
constexpr int NT = 512;      // target points
constexpr int GRID = 512;    // persistent blocks; 2/CU exact capacity -> 64/XCD
constexpr int GPB_MAX = 96;  // max group size supported

// Workspace layout (floats):
//  Kb   : MM*1024*1024   (K raw/Schur; G only written at final step)
//  Ab   : MM*1024*1024   (diag-block inverses + L panels -> A = L^-1)
//  Tb   : MM*512*512     (trinv temp; S1/S2 at predict)
//  Ktc  : MM*NT*NC
//  alpha: MM*1024
//  acc  : MM*8   ([0]=T1 [1]=T2 [2]=trG, atomically accumulated)
constexpr size_t OFF_A     = (size_t)MM * 1024 * 1024;
constexpr size_t OFF_T     = OFF_A * 2;
constexpr size_t OFF_KTC   = OFF_T + (size_t)MM * 512 * 512;
constexpr size_t OFF_ALPHA = OFF_KTC + (size_t)MM * NT * NC;
constexpr size_t OFF_ACC   = OFF_ALPHA + (size_t)MM * 1024;

#define S5 2.2360679775f

// ---------------- barrier / registration globals -----------------------------
// Groups are formed AT RUNTIME from HW_REG_XCC_ID: every block in a group is
// on the same XCD by construction, so the group barrier needs NO cache
// maintenance (intra-XCD L2 is shared+coherent; __syncthreads drains vmcnt;
// cross-block reads are volatile = L1-bypass). Registration uses epoch-tagged
// claim slots (epoch = monotonic global gen, no reset needed across replays).
struct GBar {
  unsigned slot[GPB_MAX][16];  // one 64B line per member block
  unsigned gen[16];
};
__device__ GBar g_bar2[MM];
__device__ unsigned g_claim[MM][GPB_MAX][16];
__device__ unsigned g_gcnt = 0;
__device__ unsigned g_ggen = 0;

// fence-free group barrier (group guaranteed intra-XCD)
__device__ __forceinline__ void gbar(int m, int gb, int gpbn, unsigned& ph) {
  __syncthreads();  // emits s_waitcnt vmcnt(0): all block stores are in L2
  GBar* b = &g_bar2[m];
  const int tid = threadIdx.x;
  if (gb == 0) {
    if (tid >= 1 && tid < gpbn) {
      while (__hip_atomic_load(&b->slot[tid][0], __ATOMIC_RELAXED, __HIP_MEMORY_SCOPE_AGENT) < ph)
        __builtin_amdgcn_s_sleep(2);
    }
    __syncthreads();
    if (tid == 0) {
      asm volatile("s_waitcnt vmcnt(0)" ::: "memory");
      __hip_atomic_store(&b->gen[0], ph, __ATOMIC_RELAXED, __HIP_MEMORY_SCOPE_AGENT);
    }
    __syncthreads();
  } else {
    if (tid == 0) {
      asm volatile("s_waitcnt vmcnt(0)" ::: "memory");
      __hip_atomic_store(&b->slot[gb][0], ph, __ATOMIC_RELAXED, __HIP_MEMORY_SCOPE_AGENT);
      while (__hip_atomic_load(&b->gen[0], __ATOMIC_RELAXED, __HIP_MEMORY_SCOPE_AGENT) < ph)
        __builtin_amdgcn_s_sleep(4);
    }
    __syncthreads();
  }
  ph++;
}

__device__ __forceinline__ float sigmf(float x) { return 1.0f / (1.0f + expf(-x)); }
__device__ __forceinline__ float softplusf(float x) { return fmaxf(x, 0.0f) + log1pf(expf(-fabsf(x))); }

__device__ __forceinline__ void lt_decode(int x, int& i, int& j) {
  int ii = 0;
  while ((ii + 1) * (ii + 2) / 2 <= x) ++ii;
  i = ii; j = x - ii * (ii + 1) / 2;
}

// Shared-memory struct (~47.5 KB -> 2 blocks/CU)
struct SMem {
  float Ls[64 * 65];
  float Us[64 * 65];
  float Tt[32 * 33];
  float dvec[64];
  float As[16][68];
  float Bs[16][68];
  float xi[64][3];
  float xj[64][3];
  float ai[64];
  float aj[64];
  float red[4][4];
  unsigned bar0;
  int m, rank, gpbn;
};

// ---------------- 64x64-tile GEMM, register-prefetch double-buffered ---------
// A/B volatile: cross-block data bypasses L1, reads intra-XCD-coherent L2.
template <int TA, int TB>
__device__ __forceinline__ void gemm64(const volatile float* __restrict__ A, int lda,
                                       const volatile float* __restrict__ B, int ldb,
                                       int kBeg, int kEnd, float acc[4][4], SMem& sm) {
  int tid = threadIdx.x, tx = tid & 15, ty = tid >> 4;
  float ra[4], rb[4];
  auto ldAB = [&](int k0) {
#pragma unroll
    for (int q = 0; q < 4; ++q) {
      int e = tid + (q << 8);
      if (TA) { int kk = e >> 6, r = e & 63; ra[q] = A[(size_t)(k0 + kk) * lda + r]; }
      else    { int r = e >> 4, kk = e & 15; ra[q] = A[(size_t)r * lda + k0 + kk]; }
      if (TB) { int c = e >> 4, kk = e & 15; rb[q] = B[(size_t)c * ldb + k0 + kk]; }
      else    { int kk = e >> 6, c = e & 63; rb[q] = B[(size_t)(k0 + kk) * ldb + c]; }
    }
  };
  ldAB(kBeg);
  for (int k0 = kBeg; k0 < kEnd; k0 += 16) {
    __syncthreads();
#pragma unroll
    for (int q = 0; q < 4; ++q) {
      int e = tid + (q << 8);
      if (TA) sm.As[e >> 6][e & 63] = ra[q]; else sm.As[e & 15][e >> 4] = ra[q];
      if (TB) sm.Bs[e & 15][e >> 4] = rb[q]; else sm.Bs[e >> 6][e & 63] = rb[q];
    }
    __syncthreads();
    if (k0 + 16 < kEnd) ldAB(k0 + 16);
#pragma unroll
    for (int kk = 0; kk < 16; ++kk) {
      float a[4], b[4];
#pragma unroll
      for (int i = 0; i < 4; ++i) a[i] = sm.As[kk][ty * 4 + i];
#pragma unroll
      for (int j = 0; j < 4; ++j) b[j] = sm.Bs[kk][tx * 4 + j];
#pragma unroll
      for (int i = 0; i < 4; ++i)
#pragma unroll
        for (int j = 0; j < 4; ++j) acc[i][j] = fmaf(a[i], b[j], acc[i][j]);
    }
  }
}

// ---------------- in-LDS 64x64 SPD factor + triangular inverse ---------------
__device__ void factor64(SMem& sm, float* Uout, int ldu) {
  int tid = threadIdx.x;
  int tx = tid & 15, ty = tid >> 4;
  for (int j = 0; j < 63; ++j) {
    float rinv = 1.0f / sm.Ls[j * 65 + j];
    for (int i = j + 1 + ty; i < 64; i += 16) {
      float lij = sm.Ls[i * 65 + j] * rinv;
      for (int c = j + 1 + tx; c <= i; c += 16) sm.Ls[i * 65 + c] -= lij * sm.Ls[c * 65 + j];
    }
    __syncthreads();
  }
  if (tid < 64) sm.dvec[tid] = 1.0f / sqrtf(sm.Ls[tid * 65 + tid]);
  __syncthreads();
  for (int e = tid; e < 4096; e += 256) { int r = e >> 6, c = e & 63; if (c <= r) sm.Ls[r * 65 + c] *= sm.dvec[c]; }
  __syncthreads();
  for (int e = tid; e < 64 * 65; e += 256) sm.Us[e] = 0.0f;
  __syncthreads();
  if (tid < 64) {
    int b = tid >> 5, c0 = tid & 31, base = b * 32, gc = base + c0;
    sm.Us[gc * 65 + gc] = 1.0f / sm.Ls[gc * 65 + gc];
    for (int r = c0 + 1; r < 32; ++r) {
      int gr = base + r;
      float acc = 0.0f;
      for (int l = c0; l < r; ++l) acc += sm.Ls[gr * 65 + base + l] * sm.Us[(base + l) * 65 + gc];
      sm.Us[gr * 65 + gc] = -acc / sm.Ls[gr * 65 + gr];
    }
  }
  __syncthreads();
  for (int e = tid; e < 1024; e += 256) {
    int r = e >> 5, c = e & 31;
    float acc = 0.0f;
    for (int l = c; l < 32; ++l) acc += sm.Ls[(32 + r) * 65 + l] * sm.Us[l * 65 + c];
    sm.Tt[r * 33 + c] = acc;
  }
  __syncthreads();
  for (int e = tid; e < 1024; e += 256) {
    int r = e >> 5, c = e & 31;
    float acc = 0.0f;
    for (int l = 0; l <= r; ++l) acc += sm.Us[(32 + r) * 65 + 32 + l] * sm.Tt[l * 33 + c];
    sm.Us[(32 + r) * 65 + c] = -acc;
  }
  __syncthreads();
  for (int e = tid; e < 4096; e += 256) { int r = e >> 6, c = e & 63; Uout[(size_t)r * ldu + c] = sm.Us[r * 65 + c]; }
}

// ---------------- phase bodies -----------------------------------------------

// Replicated Adam: all blocks, deterministic => bit-identical state everywhere.
__device__ void adam_all(const float* __restrict__ yc, const float* __restrict__ ws,
                         int pn, int tstep, int m, int tid, SMem& sm,
                         float praw[4], float pm[4], float pv[4],
                         float& ls, float& os, float& noi, float& cm) {
  const volatile float* al = ws + OFF_ALPHA + (size_t)m * 1024;
  const volatile float* accp = ws + OFF_ACC + m * 8;
  const float* ym = yc + (size_t)m * NC;
  float t4 = 0, t5 = 0, t6 = 0;
  for (int i = tid; i < pn; i += 256) {
    float a = al[i];
    t4 = fmaf(a, a, t4); t5 += a; t6 = fmaf(ym[i] - cm, a, t6);
  }
  for (int off = 32; off; off >>= 1) {
    t4 += __shfl_down(t4, off); t5 += __shfl_down(t5, off); t6 += __shfl_down(t6, off);
  }
  int wid = tid >> 6, lane = tid & 63;
  if (lane == 0) { sm.red[wid][0] = t4; sm.red[wid][1] = t5; sm.red[wid][2] = t6; }
  __syncthreads();
  t4 = sm.red[0][0] + sm.red[1][0] + sm.red[2][0] + sm.red[3][0];
  t5 = sm.red[0][1] + sm.red[1][1] + sm.red[2][1] + sm.red[3][1];
  t6 = sm.red[0][2] + sm.red[1][2] + sm.red[2][2] + sm.red[3][2];
  float T1 = accp[0], T2 = accp[1], t3 = accp[2];
  float fn = (float)pn;
  float g_ls = 0.5f / fn * (T1 - T2);
  float g_os = 0.5f / (fn * os) * (fn - noi * t3 - t6 + noi * t4);
  float g_no = 0.5f / fn * (t3 - t4);
  float g_c = -t5 / fn;
  float gr[4];
  gr[0] = g_ls * sigmf(praw[0]);
  gr[1] = g_os * sigmf(praw[1]);
  gr[2] = g_no * sigmf(praw[2]);
  gr[3] = g_c;
  float bc1 = 1.0f - powf(0.9f, (float)tstep);
  float bc2 = 1.0f - powf(0.999f, (float)tstep);
#pragma unroll
  for (int i = 0; i < 4; ++i) {
    float mv = 0.9f * pm[i] + 0.1f * gr[i];
    float vv = 0.999f * pv[i] + 0.001f * gr[i] * gr[i];
    pm[i] = mv; pv[i] = vv;
    praw[i] = praw[i] - 0.1f * (mv / bc1) / (sqrtf(vv / bc2) + 1e-8f);
  }
  ls = softplusf(praw[0]);
  os = softplusf(praw[1]);
  noi = softplusf(praw[2]) + 1e-4f;
  cm = praw[3];
  __syncthreads();  // protect sm.red before later phases reuse sm
}

__device__ void d_buildK(const float* __restrict__ xc, float* ws, int n, int job, int m,
                         int tid, SMem& sm, float ls, float os, float noi) {
  const float* xm = xc + (size_t)m * NC * 3;
  float* Km = ws + (size_t)m * 1048576;
  float* Am = ws + OFF_A + (size_t)m * 1048576;
  float il2 = 1.0f / (ls * ls);
  int bi, bj; lt_decode(job, bi, bj);
  if (tid < 64) {
    int r = bi * 64 + tid;
    sm.xi[tid][0] = xm[r * 3 + 0]; sm.xi[tid][1] = xm[r * 3 + 1]; sm.xi[tid][2] = xm[r * 3 + 2];
  } else if (tid < 128) {
    int lr = tid - 64; int r = bj * 64 + lr;
    sm.xj[lr][0] = xm[r * 3 + 0]; sm.xj[lr][1] = xm[r * 3 + 1]; sm.xj[lr][2] = xm[r * 3 + 2];
  }
  __syncthreads();
  if (job == 0) {
    for (int e = tid; e < 4096; e += 256) {
      int r = e >> 6, c = e & 63;
      float d0 = sm.xi[r][0] - sm.xj[c][0], d1 = sm.xi[r][1] - sm.xj[c][1], d2 = sm.xi[r][2] - sm.xj[c][2];
      float r2 = d0 * d0 + d1 * d1 + d2 * d2;
      float z = fmaxf(r2 * il2, 1e-12f);
      float dd = sqrtf(z);
      float kv = os * (1.0f + S5 * dd + (5.0f / 3.0f) * z) * expf(-S5 * dd);
      if (r == c) kv += noi;
      sm.Ls[r * 65 + c] = kv;
    }
    __syncthreads();
    factor64(sm, Am, n);
  } else {
    for (int e = tid; e < 4096; e += 256) {
      int r = e >> 6, c = e & 63;
      float d0 = sm.xi[r][0] - sm.xj[c][0], d1 = sm.xi[r][1] - sm.xj[c][1], d2 = sm.xi[r][2] - sm.xj[c][2];
      float r2 = d0 * d0 + d1 * d1 + d2 * d2;
      float z = fmaxf(r2 * il2, 1e-12f);
      float dd = sqrtf(z);
      float kv = os * (1.0f + S5 * dd + (5.0f / 3.0f) * z) * expf(-S5 * dd);
      if (bi == bj && r == c) kv += noi;
      Km[(size_t)(bi * 64 + r) * n + bj * 64 + c] = kv;
    }
  }
}

__device__ void d_trail(float* ws, int k, int n, int job, int m, int tid, SMem& sm) {
  int tx = tid & 15, ty = tid >> 4;
  float* Km = ws + (size_t)m * 1048576;
  float* Am = ws + OFF_A + (size_t)m * 1048576;
  const volatile float* Linv = Am + (size_t)(k * 64) * n + k * 64;
  int di, dj; lt_decode(job, di, dj);
  int i = k + 1 + di, j = k + 1 + dj;
  float pp[4][4] = {};
  gemm64<0, 1>(Km + (size_t)(i * 64) * n + k * 64, n, Linv, n, 0, 64, pp, sm);
  __syncthreads();
#pragma unroll
  for (int ii = 0; ii < 4; ++ii)
#pragma unroll
    for (int jj = 0; jj < 4; ++jj) sm.Ls[(ty * 4 + ii) * 65 + tx * 4 + jj] = pp[ii][jj];
  if (di == dj) {
    float* P = Am + (size_t)(i * 64) * n + k * 64;
#pragma unroll
    for (int ii = 0; ii < 4; ++ii)
#pragma unroll
      for (int jj = 0; jj < 4; ++jj) P[(size_t)(ty * 4 + ii) * n + tx * 4 + jj] = pp[ii][jj];
  } else {
#pragma unroll
    for (int ii = 0; ii < 4; ++ii)
#pragma unroll
      for (int jj = 0; jj < 4; ++jj) pp[ii][jj] = 0.0f;
    gemm64<0, 1>(Km + (size_t)(j * 64) * n + k * 64, n, Linv, n, 0, 64, pp, sm);
#pragma unroll
    for (int ii = 0; ii < 4; ++ii)
#pragma unroll
      for (int jj = 0; jj < 4; ++jj) sm.Us[(ty * 4 + ii) * 65 + tx * 4 + jj] = pp[ii][jj];
  }
  __syncthreads();
  float acc[4][4] = {};
  {
    const float* Bsrc = (di == dj) ? sm.Ls : sm.Us;
    for (int l = 0; l < 64; ++l) {
      float a[4], b[4];
#pragma unroll
      for (int ii = 0; ii < 4; ++ii) a[ii] = sm.Ls[(ty * 4 + ii) * 65 + l];
#pragma unroll
      for (int jj = 0; jj < 4; ++jj) b[jj] = Bsrc[(tx * 4 + jj) * 65 + l];
#pragma unroll
      for (int ii = 0; ii < 4; ++ii)
#pragma unroll
        for (int jj = 0; jj < 4; ++jj) acc[ii][jj] = fmaf(a[ii], b[jj], acc[ii][jj]);
    }
  }
  float* C = Km + (size_t)(i * 64) * n + j * 64;
  if (job == 0) {
    const volatile float* Cv = C;
    __syncthreads();
#pragma unroll
    for (int ii = 0; ii < 4; ++ii)
#pragma unroll
      for (int jj = 0; jj < 4; ++jj)
        sm.Ls[(ty * 4 + ii) * 65 + tx * 4 + jj] =
            Cv[(size_t)(ty * 4 + ii) * n + tx * 4 + jj] - acc[ii][jj];
    __syncthreads();
    factor64(sm, Am + (size_t)((k + 1) * 64) * n + (k + 1) * 64, n);
  } else {
    const volatile float* Cv = C;
#pragma unroll
    for (int ii = 0; ii < 4; ++ii)
#pragma unroll
      for (int jj = 0; jj < 4; ++jj)
        C[(size_t)(ty * 4 + ii) * n + tx * 4 + jj] =
            Cv[(size_t)(ty * 4 + ii) * n + tx * 4 + jj] - acc[ii][jj];
  }
}

__device__ void d_trinv64(float* ws, int n, int p, int m, int tid, SMem& sm) {
  int tx = tid & 15, ty = tid >> 4;
  float* Am = ws + OFF_A + (size_t)m * 1048576;
  const volatile float* Av = Am;
  int rb = (2 * p + 1) * 64, cb = 2 * p * 64;
  for (int e = tid; e < 4096; e += 256) {
    int r = e >> 6, c = e & 63;
    sm.Ls[r * 65 + c] = Av[(size_t)(rb + r) * n + cb + c];  // L21
    sm.Us[r * 65 + c] = Av[(size_t)(cb + r) * n + cb + c];  // A11
  }
  __syncthreads();
  float tt[4][4] = {};
  for (int l = 0; l < 64; ++l) {
    float a[4], b[4];
#pragma unroll
    for (int ii = 0; ii < 4; ++ii) a[ii] = sm.Ls[(ty * 4 + ii) * 65 + l];
#pragma unroll
    for (int jj = 0; jj < 4; ++jj) b[jj] = sm.Us[l * 65 + tx * 4 + jj];
#pragma unroll
    for (int ii = 0; ii < 4; ++ii)
#pragma unroll
      for (int jj = 0; jj < 4; ++jj) tt[ii][jj] = fmaf(a[ii], b[jj], tt[ii][jj]);
  }
  __syncthreads();
#pragma unroll
  for (int ii = 0; ii < 4; ++ii)
#pragma unroll
    for (int jj = 0; jj < 4; ++jj) sm.Ls[(ty * 4 + ii) * 65 + tx * 4 + jj] = tt[ii][jj];
  for (int e = tid; e < 4096; e += 256) {
    int r = e >> 6, c = e & 63;
    sm.Us[r * 65 + c] = Av[(size_t)(rb + r) * n + rb + c];  // A22
  }
  __syncthreads();
  float oo[4][4] = {};
  for (int l = 0; l < 64; ++l) {
    float a[4], b[4];
#pragma unroll
    for (int ii = 0; ii < 4; ++ii) a[ii] = sm.Us[(ty * 4 + ii) * 65 + l];
#pragma unroll
    for (int jj = 0; jj < 4; ++jj) b[jj] = sm.Ls[l * 65 + tx * 4 + jj];
#pragma unroll
    for (int ii = 0; ii < 4; ++ii)
#pragma unroll
      for (int jj = 0; jj < 4; ++jj) oo[ii][jj] = fmaf(a[ii], b[jj], oo[ii][jj]);
  }
#pragma unroll
  for (int ii = 0; ii < 4; ++ii)
#pragma unroll
    for (int jj = 0; jj < 4; ++jj)
      Am[(size_t)(rb + ty * 4 + ii) * n + cb + tx * 4 + jj] = -oo[ii][jj];
}

__device__ void d_trinvT(float* ws, int s, int n, int job, int m, int tid, SMem& sm) {
  int tx = tid & 15, ty = tid >> 4;
  float* Am = ws + OFF_A + (size_t)m * 1048576;
  float* Tm = ws + OFF_T + (size_t)m * 262144;
  int st = s >> 6;
  int p = job / (st * st), rem = job % (st * st);
  int ti = rem / st, tj = rem % st;
  int base = p * 2 * s;
  float acc[4][4] = {};
  gemm64<0, 0>(Am + (size_t)(base + s + ti * 64) * n + base, n,
               Am + (size_t)base * n + base + tj * 64, n, tj * 64, s, acc, sm);
  float* C = Tm + (size_t)p * s * s + (size_t)(ti * 64) * s + tj * 64;
#pragma unroll
  for (int ii = 0; ii < 4; ++ii)
#pragma unroll
    for (int jj = 0; jj < 4; ++jj) C[(size_t)(ty * 4 + ii) * s + tx * 4 + jj] = acc[ii][jj];
}

__device__ void d_trinvA(float* ws, int s, int n, int job, int m, int tid, SMem& sm) {
  int tx = tid & 15, ty = tid >> 4;
  float* Am = ws + OFF_A + (size_t)m * 1048576;
  const volatile float* Tm = ws + OFF_T + (size_t)m * 262144;
  int st = s >> 6;
  int p = job / (st * st), rem = job % (st * st);
  int ti = rem / st, tj = rem % st;
  int base = p * 2 * s;
  float acc[4][4] = {};
  gemm64<0, 0>(Am + (size_t)(base + s + ti * 64) * n + base + s, n,
               Tm + (size_t)p * s * s + tj * 64, s, 0, (ti + 1) * 64, acc, sm);
  float* C = Am + (size_t)(base + s + ti * 64) * n + base + tj * 64;
#pragma unroll
  for (int ii = 0; ii < 4; ++ii)
#pragma unroll
    for (int jj = 0; jj < 4; ++jj) C[(size_t)(ty * 4 + ii) * n + tx * 4 + jj] = -acc[ii][jj];
}

// syrk G=A^T A, fused: alpha += G(y-c), tr(G), a1 = <G,C> (G tile in regs;
// C recomputed from x). G stored only when writeG (final step).
__device__ void d_syrkAT(const float* __restrict__ yc, const float* __restrict__ xc,
                         float* ws, int n, int job, int m, int tid, SMem& sm,
                         float cm, float ls, float os, bool writeG) {
  int tx = tid & 15, ty = tid >> 4;
  const float* Am = ws + OFF_A + (size_t)m * 1048576;
  float* Gm = ws + (size_t)m * 1048576;
  const float* ym = yc + (size_t)m * NC;
  const float* xm = xc + (size_t)m * NC * 3;
  float* accp = ws + OFF_ACC + m * 8;
  float* al = ws + OFF_ALPHA + (size_t)m * 1024;
  int ib, jb; lt_decode(job, ib, jb);
  if (tid < 64) {
    int r = ib * 64 + tid;
    sm.ai[tid] = ym[r] - cm;
    sm.xi[tid][0] = xm[r * 3 + 0]; sm.xi[tid][1] = xm[r * 3 + 1]; sm.xi[tid][2] = xm[r * 3 + 2];
  } else if (tid < 128) {
    int lr = tid - 64; int r = jb * 64 + lr;
    sm.aj[lr] = ym[r] - cm;
    sm.xj[lr][0] = xm[r * 3 + 0]; sm.xj[lr][1] = xm[r * 3 + 1]; sm.xj[lr][2] = xm[r * 3 + 2];
  }
  float acc[4][4] = {};
  gemm64<1, 0>(Am + ib * 64, n, Am + jb * 64, n, ib * 64, n, acc, sm);
  if (writeG) {
#pragma unroll
    for (int ii = 0; ii < 4; ++ii)
#pragma unroll
      for (int jj = 0; jj < 4; ++jj) {
        int r = ty * 4 + ii, c = tx * 4 + jj;
        Gm[(size_t)(ib * 64 + r) * n + jb * 64 + c] = acc[ii][jj];
        if (ib != jb) Gm[(size_t)(jb * 64 + c) * n + ib * 64 + r] = acc[ii][jj];
      }
  }
  if (ib == jb && tx == ty) {
    atomicAdd(&accp[2], acc[0][0] + acc[1][1] + acc[2][2] + acc[3][3]);
  }
  float rowp[4];
#pragma unroll
  for (int i = 0; i < 4; ++i) {
    float s = 0.0f;
#pragma unroll
    for (int j = 0; j < 4; ++j) s = fmaf(acc[i][j], sm.aj[tx * 4 + j], s);
    rowp[i] = s;
  }
  float colp[4];
  if (ib != jb) {
#pragma unroll
    for (int j = 0; j < 4; ++j) {
      float s = 0.0f;
#pragma unroll
      for (int i = 0; i < 4; ++i) s = fmaf(acc[i][j], sm.ai[ty * 4 + i], s);
      colp[j] = s;
    }
  }
  float il2 = 1.0f / (ls * ls);
  float c53 = (5.0f / 3.0f) * os / ls;
  float a1 = 0.0f;
#pragma unroll
  for (int ii = 0; ii < 4; ++ii) {
    int r = ty * 4 + ii;
#pragma unroll
    for (int jj = 0; jj < 4; ++jj) {
      int c = tx * 4 + jj;
      float d0 = sm.xi[r][0] - sm.xj[c][0], d1 = sm.xi[r][1] - sm.xj[c][1], d2 = sm.xi[r][2] - sm.xj[c][2];
      float r2 = d0 * d0 + d1 * d1 + d2 * d2;
      float z = fmaxf(r2 * il2, 1e-12f);
      float dd = sqrtf(z);
      float Cv = c53 * z * (1.0f + S5 * dd) * expf(-S5 * dd);
      a1 = fmaf(acc[ii][jj], Cv, a1);
    }
  }
  a1 *= (ib == jb) ? 1.0f : 2.0f;
  for (int off = 32; off; off >>= 1) a1 += __shfl_down(a1, off);
  int wid = tid >> 6, lane = tid & 63;
  if (lane == 0) sm.red[wid][0] = a1;
  __syncthreads();
  if (tid == 0)
    atomicAdd(&accp[0], sm.red[0][0] + sm.red[1][0] + sm.red[2][0] + sm.red[3][0]);
  float* redA = &sm.As[0][0];
  float* redB = &sm.Bs[0][0];
#pragma unroll
  for (int i = 0; i < 4; ++i) redA[(ty * 4 + i) * 16 + tx] = rowp[i];
  if (ib != jb) {
#pragma unroll
    for (int j = 0; j < 4; ++j) redB[(tx * 4 + j) * 16 + ty] = colp[j];
  }
  __syncthreads();
  if (tid < 64) {
    float s = 0.0f;
#pragma unroll
    for (int q = 0; q < 16; ++q) s += redA[tid * 16 + q];
    atomicAdd(&al[ib * 64 + tid], s);
    if (ib != jb) {
      float s2 = 0.0f;
#pragma unroll
      for (int q = 0; q < 16; ++q) s2 += redB[tid * 16 + q];
      atomicAdd(&al[jb * 64 + tid], s2);
    }
  }
}

// a2 = alpha^T C alpha only (a1 fused into syrk; no G reads)
__device__ void d_reduce2(const float* __restrict__ xc, float* ws, int n, int job, int m,
                          int tid, SMem& sm, float ls, float os) {
  const float* xm = xc + (size_t)m * NC * 3;
  const volatile float* al = ws + OFF_ALPHA + (size_t)m * 1024;
  float* accp = ws + OFF_ACC + m * 8;
  float il2 = 1.0f / (ls * ls);
  float c53 = (5.0f / 3.0f) * os / ls;
  int bi, bj; lt_decode(job, bi, bj);
  float w = (bi == bj) ? 1.0f : 2.0f;
  if (tid < 64) {
    int r = bi * 64 + tid;
    sm.xi[tid][0] = xm[r * 3 + 0]; sm.xi[tid][1] = xm[r * 3 + 1]; sm.xi[tid][2] = xm[r * 3 + 2];
    sm.ai[tid] = al[r];
  } else if (tid < 128) {
    int lr = tid - 64; int r = bj * 64 + lr;
    sm.xj[lr][0] = xm[r * 3 + 0]; sm.xj[lr][1] = xm[r * 3 + 1]; sm.xj[lr][2] = xm[r * 3 + 2];
    sm.aj[lr] = al[r];
  }
  __syncthreads();
  float a2 = 0.0f;
  for (int e = tid; e < 4096; e += 256) {
    int r = e >> 6, c = e & 63;
    float d0 = sm.xi[r][0] - sm.xj[c][0], d1 = sm.xi[r][1] - sm.xj[c][1], d2 = sm.xi[r][2] - sm.xj[c][2];
    float r2 = d0 * d0 + d1 * d1 + d2 * d2;
    float z = fmaxf(r2 * il2, 1e-12f);
    float dd = sqrtf(z);
    float Cv = c53 * z * (1.0f + S5 * dd) * expf(-S5 * dd);
    a2 = fmaf(sm.ai[r] * sm.aj[c], Cv, a2);
  }
  a2 *= w;
  for (int off = 32; off; off >>= 1) a2 += __shfl_down(a2, off);
  int wid = tid >> 6, lane = tid & 63;
  if (lane == 0) sm.red[wid][1] = a2;
  __syncthreads();
  if (tid == 0) {
    atomicAdd(&accp[1], sm.red[0][1] + sm.red[1][1] + sm.red[2][1] + sm.red[3][1]);
  }
}

__device__ void d_buildKtc(const float* __restrict__ xt, const float* __restrict__ xc,
                           float* ws, int job, int m, int tid, SMem& sm, float ls, float os) {
  const float* xtm = xt + (size_t)m * NT * 3;
  const float* xm = xc + (size_t)m * NC * 3;
  float* Kt = ws + OFF_KTC + (size_t)m * NT * NC;
  float* Tm = ws + OFF_T + (size_t)m * 262144;  // S1 at Tm, S2 at Tm+NT
  float il2 = 1.0f / (ls * ls);
  if (job < 2) {
    int z = job * 256 + tid;
    Tm[z] = 0.0f; Tm[NT + z] = 0.0f;
  }
  int ti = job >> 4, tj = job & 15;
  if (tid < 64) {
    int r = ti * 64 + tid;
    sm.xi[tid][0] = xtm[r * 3 + 0]; sm.xi[tid][1] = xtm[r * 3 + 1]; sm.xi[tid][2] = xtm[r * 3 + 2];
  } else if (tid < 128) {
    int lr = tid - 64; int r = tj * 64 + lr;
    sm.xj[lr][0] = xm[r * 3 + 0]; sm.xj[lr][1] = xm[r * 3 + 1]; sm.xj[lr][2] = xm[r * 3 + 2];
  }
  __syncthreads();
  for (int e = tid; e < 4096; e += 256) {
    int r = e >> 6, c = e & 63;
    float d0 = sm.xi[r][0] - sm.xj[c][0], d1 = sm.xi[r][1] - sm.xj[c][1], d2 = sm.xi[r][2] - sm.xj[c][2];
    float r2 = d0 * d0 + d1 * d1 + d2 * d2;
    float z = fmaxf(r2 * il2, 1e-12f);
    float dd = sqrtf(z);
    float kv = os * (1.0f + S5 * dd + (5.0f / 3.0f) * z) * expf(-S5 * dd);
    Kt[(size_t)(ti * 64 + r) * NC + tj * 64 + c] = kv;
  }
}

__device__ void d_predW(float* ws, int job, int m, int tid, SMem& sm) {
  int tx = tid & 15, ty = tid >> 4;
  const volatile float* Kt = ws + OFF_KTC + (size_t)m * NT * NC;
  const volatile float* Gm = ws + (size_t)m * 1048576;
  const volatile float* al = ws + OFF_ALPHA + (size_t)m * 1024;
  float* S1 = ws + OFF_T + (size_t)m * 262144;
  float* S2 = S1 + NT;
  int ti = job >> 4, tj = job & 15;
  if (tid < 64) sm.aj[tid] = al[tj * 64 + tid];
  float acc[4][4] = {};
  gemm64<0, 0>(Kt + (size_t)(ti * 64) * NC, NC, Gm + tj * 64, 1024, 0, 1024, acc, sm);
  float s1p[4], s2p[4];
#pragma unroll
  for (int i = 0; i < 4; ++i) {
    float a1 = 0.0f, a2 = 0.0f;
    const volatile float* kr = Kt + (size_t)(ti * 64 + ty * 4 + i) * NC + tj * 64;
#pragma unroll
    for (int j = 0; j < 4; ++j) {
      float kv = kr[tx * 4 + j];
      a1 = fmaf(kv, sm.aj[tx * 4 + j], a1);
      a2 = fmaf(kv, acc[i][j], a2);
    }
    s1p[i] = a1; s2p[i] = a2;
  }
  __syncthreads();
  float* redA = &sm.As[0][0];
  float* redB = &sm.Bs[0][0];
#pragma unroll
  for (int i = 0; i < 4; ++i) {
    redA[(ty * 4 + i) * 16 + tx] = s1p[i];
    redB[(ty * 4 + i) * 16 + tx] = s2p[i];
  }
  __syncthreads();
  if (tid < 64) {
    float a1 = 0.0f, a2 = 0.0f;
#pragma unroll
    for (int q = 0; q < 16; ++q) { a1 += redA[tid * 16 + q]; a2 += redB[tid * 16 + q]; }
    atomicAdd(&S1[ti * 64 + tid], a1);
    atomicAdd(&S2[ti * 64 + tid], a2);
  }
}

// ---------------- persistent mega-kernel, runtime XCD-derived groups ---------
__global__ __launch_bounds__(256, 2) void k_gp(const float* __restrict__ xc,
                                               const float* __restrict__ yc,
                                               const float* __restrict__ xt,
                                               float* ws, float* out) {
  __shared__ SMem sm;
  const int tid = threadIdx.x;

  // ---- registration: group = OWN XCD (read from HW), rank via epoch-tagged
  // claim slots; one full-fence global barrier settles membership. Monotonic
  // epoch => no reset across graph replays. Exact capacity (512 = 256CU x 2)
  // guarantees all blocks co-resident and 64 per XCD.
  if (tid == 0) {
    unsigned G0 = __hip_atomic_load(&g_ggen, __ATOMIC_RELAXED, __HIP_MEMORY_SCOPE_AGENT);
    unsigned E = G0 + 1u;
    unsigned x;
    asm volatile("s_getreg_b32 %0, hwreg(HW_REG_XCC_ID)" : "=s"(x));
    x &= 7u;
    int r = 0;
    for (int i = 0; i < GPB_MAX; ++i) {
      unsigned old = __hip_atomic_exchange(&g_claim[x][i][0], E, __ATOMIC_RELAXED, __HIP_MEMORY_SCOPE_AGENT);
      if (old != E) { r = i; break; }
    }
    __threadfence();
    unsigned a = __hip_atomic_fetch_add(&g_gcnt, 1u, __ATOMIC_ACQ_REL, __HIP_MEMORY_SCOPE_AGENT);
    if (a + 1u == (unsigned)GRID) {
      __hip_atomic_store(&g_gcnt, 0u, __ATOMIC_RELAXED, __HIP_MEMORY_SCOPE_AGENT);
      __hip_atomic_store(&g_ggen, E, __ATOMIC_RELEASE, __HIP_MEMORY_SCOPE_AGENT);
    } else {
      while (__hip_atomic_load(&g_ggen, __ATOMIC_ACQUIRE, __HIP_MEMORY_SCOPE_AGENT) < E)
        __builtin_amdgcn_s_sleep(16);
    }
    __threadfence();
    int n = 0;
    for (int i = 0; i < GPB_MAX; ++i)
      n += (__hip_atomic_load(&g_claim[x][i][0], __ATOMIC_RELAXED, __HIP_MEMORY_SCOPE_AGENT) == E);
    sm.m = (int)x; sm.rank = r; sm.gpbn = n;
    sm.bar0 = __hip_atomic_load(&g_bar2[x].gen[0], __ATOMIC_RELAXED, __HIP_MEMORY_SCOPE_AGENT);
  }
  __syncthreads();
  const int m = sm.m, gb = sm.rank, gpbn = sm.gpbn;
  unsigned ph = sm.bar0 + 1;

  // replicated per-block Adam/param state (bit-identical across blocks)
  float praw[4] = {0.f, 0.f, 0.f, 0.f};
  float pm[4]   = {0.f, 0.f, 0.f, 0.f};
  float pv[4]   = {0.f, 0.f, 0.f, 0.f};
  float ls = 0.69314718056f, os = 0.69314718056f;
  float noi = 0.69314718056f + 1e-4f, cm = 0.0f;

  for (int step = 0; step < 17; ++step) {
    const int n = step < 8 ? 512 : 1024;
    const int nb = n >> 6;
    const bool lastStep = (step == 16);

    // ---- merged phase: replicated Adam + buildK (factor(0,0) on rank 0) ----
    if (step > 0) {
      adam_all(yc, ws, step <= 8 ? 512 : 1024, step, m, tid, sm,
               praw, pm, pv, ls, os, noi, cm);
    }
    {
      const int tot = nb * (nb + 1) / 2;
      if (gb == 0) {
        __syncthreads();
        __builtin_amdgcn_s_setprio(1);  // critical path: factor chain
        d_buildK(xc, ws, n, 0, m, tid, sm, ls, os, noi);
        __builtin_amdgcn_s_setprio(0);
      } else {
        for (int q = gb; q < tot; q += gpbn - 1) {
          __syncthreads();
          d_buildK(xc, ws, n, q, m, tid, sm, ls, os, noi);
        }
      }
      gbar(m, gb, gpbn, ph);
    }

    // ---- Cholesky trailing updates; rank0 owns the factor job; trinv64 pair
    // p=k>>1 folded onto last rank at odd k (inputs complete at barrier k-1).
    for (int k = 0; k <= nb - 2; ++k) {
      const int t = nb - 1 - k;
      const int tot = t * (t + 1) / 2;
      if (gb == 0) {
        if (k == 0) {  // zero alpha/acc (post-adam-read, pre-syrk-accumulate)
          float* al = ws + OFF_ALPHA + (size_t)m * 1024;
          for (int z = tid; z < 1024; z += 256) al[z] = 0.0f;
          if (tid < 8) ws[OFF_ACC + m * 8 + tid] = 0.0f;
        }
        __syncthreads();
        __builtin_amdgcn_s_setprio(1);  // critical path: Schur(0)+factor(k+1)
        d_trail(ws, k, n, 0, m, tid, sm);
        __builtin_amdgcn_s_setprio(0);
      } else {
        for (int q = gb; q < tot; q += gpbn - 1) {
          __syncthreads();
          d_trail(ws, k, n, q, m, tid, sm);
        }
        if ((k & 1) && gb == gpbn - 1) {
          __syncthreads();
          d_trinv64(ws, n, k >> 1, m, tid, sm);
        }
      }
      gbar(m, gb, gpbn, ph);
    }

    for (int s = 128; s < n; s <<= 1) {  // trinv higher levels
      const int st = s >> 6;
      const int np = n / (2 * s);
      const int tot = np * st * st;
      for (int q = gb; q < tot; q += gpbn) {
        __syncthreads();
        d_trinvT(ws, s, n, q, m, tid, sm);
      }
      if (s == 128 && gb == gpbn - 1) {  // leftover trinv64 pair (nb/2-1)
        __syncthreads();
        d_trinv64(ws, n, nb / 2 - 1, m, tid, sm);
      }
      gbar(m, gb, gpbn, ph);
      for (int q = gb; q < tot; q += gpbn) {
        __syncthreads();
        d_trinvA(ws, s, n, q, m, tid, sm);
      }
      gbar(m, gb, gpbn, ph);
    }

    {  // syrk + fused alpha/trace/a1; snake job order balances the K-skew
      const int tot = nb * (nb + 1) / 2;
      for (int t = 0;; ++t) {
        int base = t * gpbn;
        if (base >= tot) break;
        int q = base + ((t & 1) ? (gpbn - 1 - gb) : gb);
        if (q < tot) {
          __syncthreads();
          d_syrkAT(yc, xc, ws, n, q, m, tid, sm, cm, ls, os, lastStep);
        }
      }
      gbar(m, gb, gpbn, ph);
    }

    if (step < 16) {  // a2 = alpha^T C alpha (needs completed alpha)
      const int tot = nb * (nb + 1) / 2;
      for (int q = gb; q < tot; q += gpbn) {
        __syncthreads();
        d_reduce2(xc, ws, n, q, m, tid, sm, ls, os);
      }
      gbar(m, gb, gpbn, ph);
    }
  }

  // ---- prediction (per-m) ----
  {
    for (int q = gb; q < 128; q += gpbn) {
      __syncthreads();
      d_buildKtc(xt, xc, ws, q, m, tid, sm, ls, os);
    }
    gbar(m, gb, gpbn, ph);
    for (int q = gb; q < 128; q += gpbn) {
      __syncthreads();
      d_predW(ws, q, m, tid, sm);
    }
    gbar(m, gb, gpbn, ph);
    const volatile float* S1 = ws + OFF_T + (size_t)m * 262144;
    const volatile float* S2 = S1 + NT;
    for (int t = gb * 256 + tid; t < NT; t += gpbn * 256) {
      out[(size_t)m * NT + t] = cm + S1[t];
      out[(size_t)MM * NT + (size_t)m * NT + t] = os + noi - S2[t];
    }
  }
}

// ---------------- host: single plain launch ----------------------------------
extern "C" void kernel_launch(void* const* d_in, const int* in_sizes, int n_in,
                              void* d_out, int out_size, void* d_ws, size_t ws_size,
                              hipStream_t stream) {
  const float* xc = (const float*)d_in[0];
  const float* yc = (const float*)d_in[1];
  const float* xt = (const float*)d_in[2];
  float* out = (float*)d_out;
  float* ws = (float*)d_ws;

  hipLaunchKernelGGL(k_gp, dim3(GRID), dim3(256), 0, stream, xc, yc, xt, ws, out);

  (void)in_sizes; (void)n_in; (void)out_size; (void)ws_size;
}